// Round 4
// baseline (500.693 us; speedup 1.0000x reference)
//
#include <hip/hip_runtime.h>

// Caps layer: B=256 batches, S=512 input caps, D=256 in-dim, NC=16, DC=32, O=512.
// One block per batch, 1024 threads (16 waves -> 50% occupancy/CU).
// Factorized routing (u_hat never materialized):
//   y[n][D]   = sum_s c[n][s] x[s][D]
//   outputs   = squash_d( y[n] . W[:, n*32+d] )
//   z[n][D]   = sum_d W[D][n*32+d] outputs[n][d]
//   b[n][s]   = sum_D x[s][D] z[n][D]           (MFMA 16x16x32 bf16, fp32 acc)

#define S_ 512
#define D_ 256
#define O_ 512

typedef __attribute__((ext_vector_type(8))) short short8;
typedef __attribute__((ext_vector_type(4))) float floatx4;

__device__ __forceinline__ unsigned short f2b(float f) {
  union { float ff; unsigned int i; } v; v.ff = f;
  unsigned int u = v.i;
  return (unsigned short)((u + 0x7FFFu + ((u >> 16) & 1u)) >> 16);
}

__global__ __launch_bounds__(1024, 4) void caps_kernel(
    const float* __restrict__ x, const float* __restrict__ W,
    float* __restrict__ out)
{
  // LDS budget (60416 B total):
  //   bl   f32 16x520 = 33280 B: logits b[n][s] | c^T f32 [s][16] (0..8K) | iter0 rowsum partials
  //   ytmp f32 16x260 = 16640 B: y[n][D]
  //   zb   u16 16x264 =  8448 B: z bf16 | pa f32[1024] overlay (outputs partials)
  //   outp f32 512    =  2048 B
  __shared__ __align__(16) float bl[16 * 520];
  __shared__ __align__(16) float ytmp[16 * 260];
  __shared__ __align__(16) unsigned short zb[16 * 264];
  __shared__ __align__(16) float outp[O_];

  float* pa = (float*)zb;

  const int tid  = threadIdx.x;
  const int wave = tid >> 6;
  const int lane = tid & 63;
  const float* xb = x + (size_t)blockIdx.x * (S_ * D_);

  for (int it = 0; it < 3; ++it) {
    if (it == 0) {
      // ---- iter 0: b=0 -> c=1/16 uniform -> y[n][:] = (1/16)*rowsum(x), all n equal
      float a0 = 0.f, a1 = 0.f, a2 = 0.f, a3 = 0.f;
      #pragma unroll 4
      for (int r = 0; r < 32; ++r) {
        const int s = (wave << 5) + r;
        const float4 xv = *(const float4*)(xb + s * D_ + (lane << 2));
        a0 += xv.x; a1 += xv.y; a2 += xv.z; a3 += xv.w;
      }
      *(float4*)(bl + wave * 520 + (lane << 2)) = make_float4(a0, a1, a2, a3);
      __syncthreads();
      if (tid < 256) {
        float v = 0.f;
        #pragma unroll
        for (int w = 0; w < 16; ++w) v += bl[w * 520 + tid];
        v *= 0.0625f;
        #pragma unroll
        for (int n = 0; n < 16; ++n) ytmp[n * 260 + tid] = v;
      }
      __syncthreads();
    } else {
      // ---- softmax over n (per s): logits bl[n][s] -> c^T f32 at bl[s*16+n] ----
      float vv[16]; float inv = 0.f;
      if (tid < 512) {
        const int s = tid;
        float m = -1e30f;
        #pragma unroll
        for (int n = 0; n < 16; ++n) { vv[n] = bl[n * 520 + s]; m = fmaxf(m, vv[n]); }
        float sum = 0.f;
        #pragma unroll
        for (int n = 0; n < 16; ++n) { vv[n] = __expf(vv[n] - m); sum += vv[n]; }
        inv = 1.f / sum;
      }
      __syncthreads();   // all logit reads complete before overwrite
      if (tid < 512) {
        const int s = tid;
        *(float4*)(bl + s * 16)      = make_float4(vv[0]*inv,  vv[1]*inv,  vv[2]*inv,  vv[3]*inv);
        *(float4*)(bl + s * 16 + 4)  = make_float4(vv[4]*inv,  vv[5]*inv,  vv[6]*inv,  vv[7]*inv);
        *(float4*)(bl + s * 16 + 8)  = make_float4(vv[8]*inv,  vv[9]*inv,  vv[10]*inv, vv[11]*inv);
        *(float4*)(bl + s * 16 + 12) = make_float4(vv[12]*inv, vv[13]*inv, vv[14]*inv, vv[15]*inv);
      }
      __syncthreads();
      // ---- y-pass: 16 waves = 8 s-octants x 2 n-halves; lane owns D-quad ----
      const int h   = wave & 1;        // n-half: n in [h*8, h*8+8)
      const int oct = wave >> 1;       // s-octant
      float acc[8][4];
      #pragma unroll
      for (int j = 0; j < 8; ++j) { acc[j][0]=0.f; acc[j][1]=0.f; acc[j][2]=0.f; acc[j][3]=0.f; }
      #pragma unroll 2
      for (int r = 0; r < 64; ++r) {
        const int s = (oct << 6) + r;
        const float4 xv = *(const float4*)(xb + s * D_ + (lane << 2));
        const float4 c0 = *(const float4*)(bl + s * 16 + (h << 3));      // wave-uniform
        const float4 c1 = *(const float4*)(bl + s * 16 + (h << 3) + 4);
        float cf[8];
        cf[0]=c0.x; cf[1]=c0.y; cf[2]=c0.z; cf[3]=c0.w;
        cf[4]=c1.x; cf[5]=c1.y; cf[6]=c1.z; cf[7]=c1.w;
        #pragma unroll
        for (int j = 0; j < 8; ++j) {
          acc[j][0] += cf[j] * xv.x; acc[j][1] += cf[j] * xv.y;
          acc[j][2] += cf[j] * xv.z; acc[j][3] += cf[j] * xv.w;
        }
      }
      // reduce octants into ytmp; the two n-halves write disjoint rows
      for (int rr = 0; rr < 8; ++rr) {
        if (oct == rr) {
          #pragma unroll
          for (int j = 0; j < 8; ++j) {
            const int n = (h << 3) + j;
            float4* p = (float4*)(ytmp + n * 260 + (lane << 2));
            if (rr == 0) { *p = make_float4(acc[j][0], acc[j][1], acc[j][2], acc[j][3]); }
            else { float4 v = *p; v.x += acc[j][0]; v.y += acc[j][1]; v.z += acc[j][2]; v.w += acc[j][3]; *p = v; }
          }
        }
        __syncthreads();
      }
    }

    // ---- outputs[n][d] = sum_D y[n][D] * W[D][n*32+d] (split D over 2 halves) ----
    {
      const int o    = tid & 511;
      const int half = tid >> 9;
      const int n    = o >> 5;
      float a = 0.f;
      const int Db0 = half << 4;
      for (int Db = Db0; Db < Db0 + 16; ++Db) {
        const float4 y0 = *(const float4*)(ytmp + n * 260 + (Db << 3));
        const float4 y1 = *(const float4*)(ytmp + n * 260 + (Db << 3) + 4);
        const float* wp = W + (size_t)(Db << 3) * O_ + o;   // coalesced over o
        a += y0.x * wp[0 * O_]; a += y0.y * wp[1 * O_];
        a += y0.z * wp[2 * O_]; a += y0.w * wp[3 * O_];
        a += y1.x * wp[4 * O_]; a += y1.y * wp[5 * O_];
        a += y1.z * wp[6 * O_]; a += y1.w * wp[7 * O_];
      }
      pa[tid] = a;   // zb overlay (zb dead here)
    }
    __syncthreads();
    if (tid < 512) {
      const int o = tid;
      float a = pa[o] + pa[o + 512];
      float ss = a * a;
      #pragma unroll
      for (int off = 1; off < 32; off <<= 1) ss += __shfl_xor(ss, off, 64);
      const float v = a / sqrtf(ss + 1e-7f);
      outp[o] = v;
      if (it == 2) out[(size_t)blockIdx.x * O_ + o] = v;
    }
    __syncthreads();

    if (it < 2) {
      // ---- z[n][D] = sum_d W[D][n*32+d] * outputs[n][d]; wave owns 16 D-rows ----
      {
        const int obase = lane << 3;
        const int n_ln  = lane >> 2;
        float ov[8];
        #pragma unroll
        for (int j = 0; j < 8; ++j) ov[j] = outp[obase + j];
        for (int r = 0; r < 16; ++r) {
          const int Dd = (wave << 4) + r;
          const float4 w0 = *(const float4*)(W + (size_t)Dd * O_ + obase);
          const float4 w1 = *(const float4*)(W + (size_t)Dd * O_ + obase + 4);
          float a = w0.x * ov[0] + w0.y * ov[1] + w0.z * ov[2] + w0.w * ov[3]
                  + w1.x * ov[4] + w1.y * ov[5] + w1.z * ov[6] + w1.w * ov[7];
          a += __shfl_xor(a, 1, 64);
          a += __shfl_xor(a, 2, 64);
          if ((lane & 3) == 0) zb[n_ln * 264 + Dd] = f2b(a);
        }
      }
      __syncthreads();
      // ---- b-update via MFMA: b[16n x 16s] = z[16x256] * x^T[256x16]; 2 tiles/wave
      const int l15 = lane & 15, l4 = lane >> 4;
      for (int t = 0; t < 2; ++t) {
        const int s0 = ((wave << 1) + t) << 4;
        floatx4 C = {0.f, 0.f, 0.f, 0.f};
        #pragma unroll
        for (int k = 0; k < 8; ++k) {
          // A-frag: z[m=l15][k*32 + l4*8 + j] from LDS (528 B rows, 16B-aligned)
          const short8 A = *(const short8*)(zb + l15 * 264 + (k << 5) + (l4 << 3));
          // B-frag: x[s0+l15][k*32 + l4*8 + j] fp32 global -> bf16
          const float* xp = xb + (s0 + l15) * D_ + (k << 5) + (l4 << 3);
          const float4 xv0 = *(const float4*)xp;
          const float4 xv1 = *(const float4*)(xp + 4);
          short8 Bf;
          Bf[0] = (short)f2b(xv0.x); Bf[1] = (short)f2b(xv0.y);
          Bf[2] = (short)f2b(xv0.z); Bf[3] = (short)f2b(xv0.w);
          Bf[4] = (short)f2b(xv1.x); Bf[5] = (short)f2b(xv1.y);
          Bf[6] = (short)f2b(xv1.z); Bf[7] = (short)f2b(xv1.w);
          C = __builtin_amdgcn_mfma_f32_16x16x32_bf16(A, Bf, C, 0, 0, 0);
        }
        // C/D layout: col = lane&15 (s), row = (lane>>4)*4 + reg (n); store fp32
        #pragma unroll
        for (int rg = 0; rg < 4; ++rg)
          bl[((l4 << 2) + rg) * 520 + s0 + l15] = C[rg];
      }
      __syncthreads();
    }
  }
}

extern "C" void kernel_launch(void* const* d_in, const int* in_sizes, int n_in,
                              void* d_out, int out_size, void* d_ws, size_t ws_size,
                              hipStream_t stream) {
  const float* x = (const float*)d_in[0];   // [256, 512, 256] f32
  const float* W = (const float*)d_in[1];   // [256, 512] f32
  float* out = (float*)d_out;               // [256*512] f32
  (void)in_sizes; (void)n_in; (void)out_size; (void)d_ws; (void)ws_size;
  caps_kernel<<<256, 1024, 0, stream>>>(x, W, out);
}

// Round 5
// 300.448 us; speedup vs baseline: 1.6665x; 1.6665x over previous
//
#include <hip/hip_runtime.h>

// Caps layer: B=256 batches, S=512 input caps, D=256 in-dim, NC=16, DC=32, O=512.
// One block per batch, 512 threads (8 waves); grid 256 = 1 block/CU (structural).
// Factorized routing (u_hat never materialized):
//   y[n][D]   = sum_s c[n][s] x[s][D]
//   outputs   = squash_d( y[n] . W[:, n*32+d] )
//   z[n][D]   = sum_d W[D][n*32+d] outputs[n][d]
//   b[n][s]   = sum_D x[s][D] z[n][D]           (MFMA 16x16x32 bf16, fp32 acc)
// Key: __launch_bounds__(512,2) -> 256-VGPR budget, y-pass acc/c fully in regs
// (round 3/4 spilled: WRITE_SIZE 30-139 MB of scratch traffic at VGPR_Count=64).

#define S_ 512
#define D_ 256
#define O_ 512

typedef __attribute__((ext_vector_type(8))) short short8;
typedef __attribute__((ext_vector_type(4))) float floatx4;

__device__ __forceinline__ unsigned short f2b(float f) {
  union { float ff; unsigned int i; } v; v.ff = f;
  unsigned int u = v.i;
  return (unsigned short)((u + 0x7FFFu + ((u >> 16) & 1u)) >> 16);
}

__global__ __launch_bounds__(512, 2) void caps_kernel(
    const float* __restrict__ x, const float* __restrict__ W,
    float* __restrict__ out)
{
  // LDS (60416 B):
  //   bl   f32 16x520 = 33280 B: logits b[n][s], then c[n][s] f32 in-place;
  //                              also iter-0 rowsum strips (one 520-row per wave)
  //   ytmp f32 16x260 = 16640 B: y[n][D]
  //   zb   u16 16x264 =  8448 B: z bf16 (528 B rows)
  //   outp f32 512    =  2048 B
  __shared__ __align__(16) float bl[16 * 520];
  __shared__ __align__(16) float ytmp[16 * 260];
  __shared__ __align__(16) unsigned short zb[16 * 264];
  __shared__ __align__(16) float outp[O_];

  const int tid  = threadIdx.x;
  const int wave = tid >> 6;
  const int lane = tid & 63;
  const float* xb = x + (size_t)blockIdx.x * (S_ * D_);

  for (int it = 0; it < 3; ++it) {
    if (it == 0) {
      // ---- iter 0: b=0 -> c=1/16 uniform -> y[n][:] = (1/16)*rowsum(x) ----
      float a0 = 0.f, a1 = 0.f, a2 = 0.f, a3 = 0.f;
      #pragma unroll 4
      for (int r = 0; r < 64; ++r) {
        const int s = (wave << 6) + r;
        const float4 xv = *(const float4*)(xb + s * D_ + (lane << 2));
        a0 += xv.x; a1 += xv.y; a2 += xv.z; a3 += xv.w;
      }
      *(float4*)(bl + wave * 520 + (lane << 2)) = make_float4(a0, a1, a2, a3);
      __syncthreads();
      if (tid < 256) {
        float v = 0.f;
        #pragma unroll
        for (int w = 0; w < 8; ++w) v += bl[w * 520 + tid];
        v *= 0.0625f;
        #pragma unroll
        for (int n = 0; n < 16; ++n) ytmp[n * 260 + tid] = v;
      }
      __syncthreads();
    } else {
      // ---- softmax over n (per s), in place: bl[n][s] logits -> c f32 ----
      // Thread s owns column s exclusively: no barrier between read and write.
      {
        const int s = tid;
        float vv[16];
        float m = -1e30f;
        #pragma unroll
        for (int n = 0; n < 16; ++n) { vv[n] = bl[n * 520 + s]; m = fmaxf(m, vv[n]); }
        float sum = 0.f;
        #pragma unroll
        for (int n = 0; n < 16; ++n) { vv[n] = __expf(vv[n] - m); sum += vv[n]; }
        const float inv = 1.f / sum;
        #pragma unroll
        for (int n = 0; n < 16; ++n) bl[n * 520 + s] = vv[n] * inv;   // stride-1: no conflicts
      }
      __syncthreads();
      // ---- y-pass: wave owns s-octant, lane owns D-quad; all state in regs ----
      float acc[16][4];
      #pragma unroll
      for (int n = 0; n < 16; ++n) { acc[n][0]=0.f; acc[n][1]=0.f; acc[n][2]=0.f; acc[n][3]=0.f; }
      for (int g = 0; g < 16; ++g) {
        const int s0 = (wave << 6) + (g << 2);
        float cc[16][4];
        #pragma unroll
        for (int n = 0; n < 16; ++n) {
          const float4 c4 = *(const float4*)(bl + n * 520 + s0);   // wave-uniform b128
          cc[n][0] = c4.x; cc[n][1] = c4.y; cc[n][2] = c4.z; cc[n][3] = c4.w;
        }
        #pragma unroll
        for (int j = 0; j < 4; ++j) {
          const float4 xv = *(const float4*)(xb + (s0 + j) * D_ + (lane << 2));
          #pragma unroll
          for (int n = 0; n < 16; ++n) {
            acc[n][0] += cc[n][j] * xv.x; acc[n][1] += cc[n][j] * xv.y;
            acc[n][2] += cc[n][j] * xv.z; acc[n][3] += cc[n][j] * xv.w;
          }
        }
      }
      // octant reduction into ytmp (8 serialized rounds; ~1-2 us total)
      for (int rr = 0; rr < 8; ++rr) {
        if (wave == rr) {
          #pragma unroll
          for (int n = 0; n < 16; ++n) {
            float4* p = (float4*)(ytmp + n * 260 + (lane << 2));
            if (rr == 0) { *p = make_float4(acc[n][0], acc[n][1], acc[n][2], acc[n][3]); }
            else { float4 v = *p; v.x += acc[n][0]; v.y += acc[n][1]; v.z += acc[n][2]; v.w += acc[n][3]; *p = v; }
          }
        }
        __syncthreads();
      }
    }

    // ---- outputs[n][d] = sum_D y[n][D] * W[D][n*32+d], then squash over d ----
    {
      const int o = tid;
      const int n = o >> 5;
      float a = 0.f;
      for (int Db = 0; Db < 32; ++Db) {
        const float4 y0 = *(const float4*)(ytmp + n * 260 + (Db << 3));
        const float4 y1 = *(const float4*)(ytmp + n * 260 + (Db << 3) + 4);
        const float* wp = W + (size_t)(Db << 3) * O_ + o;   // coalesced over o
        a += y0.x * wp[0 * O_]; a += y0.y * wp[1 * O_];
        a += y0.z * wp[2 * O_]; a += y0.w * wp[3 * O_];
        a += y1.x * wp[4 * O_]; a += y1.y * wp[5 * O_];
        a += y1.z * wp[6 * O_]; a += y1.w * wp[7 * O_];
      }
      float ss = a * a;
      #pragma unroll
      for (int off = 1; off < 32; off <<= 1) ss += __shfl_xor(ss, off, 64);
      const float v = a / sqrtf(ss + 1e-7f);
      outp[o] = v;
      if (it == 2) out[(size_t)blockIdx.x * O_ + o] = v;
    }
    __syncthreads();

    if (it < 2) {
      // ---- z[n][D] = sum_d W[D][n*32+d] * outputs[n][d]; wave owns 32 D-rows ----
      {
        const int obase = lane << 3;
        const int n_ln  = lane >> 2;
        float ov[8];
        #pragma unroll
        for (int j = 0; j < 8; ++j) ov[j] = outp[obase + j];
        for (int r = 0; r < 32; ++r) {
          const int Dd = (wave << 5) + r;
          const float4 w0 = *(const float4*)(W + (size_t)Dd * O_ + obase);
          const float4 w1 = *(const float4*)(W + (size_t)Dd * O_ + obase + 4);
          float a = w0.x * ov[0] + w0.y * ov[1] + w0.z * ov[2] + w0.w * ov[3]
                  + w1.x * ov[4] + w1.y * ov[5] + w1.z * ov[6] + w1.w * ov[7];
          a += __shfl_xor(a, 1, 64);
          a += __shfl_xor(a, 2, 64);
          if ((lane & 3) == 0) zb[n_ln * 264 + Dd] = f2b(a);
        }
      }
      __syncthreads();
      // ---- b-update via MFMA: b[16n x 16s] = z[16x256] * x^T[256x16]; 4 tiles/wave
      const int l15 = lane & 15, l4 = lane >> 4;
      for (int t = 0; t < 4; ++t) {
        const int s0 = ((wave << 2) + t) << 4;
        floatx4 C = {0.f, 0.f, 0.f, 0.f};
        #pragma unroll
        for (int k = 0; k < 8; ++k) {
          // A-frag: z[m=l15][k*32 + l4*8 + j] from LDS (528 B rows, 16B-aligned)
          const short8 A = *(const short8*)(zb + l15 * 264 + (k << 5) + (l4 << 3));
          // B-frag: x[s0+l15][k*32 + l4*8 + j] fp32 global -> bf16
          const float* xp = xb + (s0 + l15) * D_ + (k << 5) + (l4 << 3);
          const float4 xv0 = *(const float4*)xp;
          const float4 xv1 = *(const float4*)(xp + 4);
          short8 Bf;
          Bf[0] = (short)f2b(xv0.x); Bf[1] = (short)f2b(xv0.y);
          Bf[2] = (short)f2b(xv0.z); Bf[3] = (short)f2b(xv0.w);
          Bf[4] = (short)f2b(xv1.x); Bf[5] = (short)f2b(xv1.y);
          Bf[6] = (short)f2b(xv1.z); Bf[7] = (short)f2b(xv1.w);
          C = __builtin_amdgcn_mfma_f32_16x16x32_bf16(A, Bf, C, 0, 0, 0);
        }
        // C/D layout: col = lane&15 (s), row = (lane>>4)*4 + reg (n); store fp32
        #pragma unroll
        for (int rg = 0; rg < 4; ++rg)
          bl[((l4 << 2) + rg) * 520 + s0 + l15] = C[rg];
      }
      __syncthreads();
    }
  }
}

extern "C" void kernel_launch(void* const* d_in, const int* in_sizes, int n_in,
                              void* d_out, int out_size, void* d_ws, size_t ws_size,
                              hipStream_t stream) {
  const float* x = (const float*)d_in[0];   // [256, 512, 256] f32
  const float* W = (const float*)d_in[1];   // [256, 512] f32
  float* out = (float*)d_out;               // [256*512] f32
  (void)in_sizes; (void)n_in; (void)out_size; (void)d_ws; (void)ws_size;
  caps_kernel<<<256, 512, 0, stream>>>(x, W, out);
}